// Round 4
// baseline (550.297 us; speedup 1.0000x reference)
//
#include <hip/hip_runtime.h>

typedef __attribute__((ext_vector_type(8))) short short8;
typedef __attribute__((ext_vector_type(4))) float f32x4;

#define SEQ 2048
#define BATCH 64
#define HID 512
#define ATT 512
#define SPB 8   // s-tiles per persistent block (grid = 256 = 1 block/CU)

__device__ __forceinline__ unsigned short f2bf(float f) {
  unsigned u = __float_as_uint(f);
  u += 0x7fffu + ((u >> 16) & 1u);   // round-to-nearest-even
  return (unsigned short)(u >> 16);
}

// Pre-kernel: blocks 0..63 compute decT[a][b] = (W_t@dec_out[b] + b_t)[a] (transposed, fp32);
// blocks 64..127 convert W_s -> bf16.
__global__ void bahdanau_pre(const float* __restrict__ dec_out,
                             const float* __restrict__ W_t,
                             const float* __restrict__ b_t,
                             const float* __restrict__ W_s,
                             unsigned short* __restrict__ wsb,
                             float* __restrict__ decT) {
  if (blockIdx.x < 64) {
    const int b = blockIdx.x;
    __shared__ float drow[HID];
    for (int i = threadIdx.x; i < HID; i += 256) drow[i] = dec_out[b * HID + i];
    __syncthreads();
    for (int a = threadIdx.x; a < ATT; a += 256) {
      const float4* wr = (const float4*)(W_t + (size_t)a * HID);
      float s0 = 0.f, s1 = 0.f, s2 = 0.f, s3 = 0.f;
#pragma unroll 4
      for (int j = 0; j < HID / 4; ++j) {
        float4 w = wr[j];
        s0 = fmaf(w.x, drow[4 * j + 0], s0);
        s1 = fmaf(w.y, drow[4 * j + 1], s1);
        s2 = fmaf(w.z, drow[4 * j + 2], s2);
        s3 = fmaf(w.w, drow[4 * j + 3], s3);
      }
      decT[a * BATCH + b] = (s0 + s1) + (s2 + s3) + b_t[a];
    }
  } else {
    const int cb = blockIdx.x - 64;
    const float4* src = (const float4*)W_s;
#pragma unroll
    for (int i = 0; i < 4; ++i) {
      int idx = cb * 1024 + i * 256 + threadIdx.x;
      float4 v = src[idx];
      ushort4 o;
      o.x = f2bf(v.x); o.y = f2bf(v.y); o.z = f2bf(v.z); o.w = f2bf(v.w);
      ((ushort4*)wsb)[idx] = o;
    }
  }
}

// Persistent main: 256 blocks x 1024 thr (16 waves, 4/SIMD via launch_bounds cap).
// Wave w: n-slice n0=32w, computes 64m x 32n (acc 32 VGPR). A-tile in double-buffered
// bf16 LDS; the 8 HBM A-burst loads for tile si+1 are issued BEFORE any B loads of
// tile si (vmcnt FIFO stays clean: every B-frag wait sees only L2-aged older entries),
// consumed (cvt->LDS) after the K-loop. One barrier per tile; only L2 tails drain.
__global__ __launch_bounds__(1024, 4)
void bahdanau_main(const float* __restrict__ enc,
                   const unsigned short* __restrict__ wsb,
                   const float* __restrict__ decT,
                   const float* __restrict__ v_a,
                   float* __restrict__ out) {
  // A chunk kk (64 rows x 32 k): element (row, k=qk*8+j) at [kk*2080 + (qk*65+row)*8 + j]
  __shared__ __align__(16) unsigned short Albuf[2][16 * 2080];  // 2 x 66560 B
  __shared__ float partial[2][16 * 64];                         // 8 KB -> 141 KB total

  const int tid  = threadIdx.x;
  const int wave = tid >> 6;
  const int lane = tid & 63;
  const int c = lane & 15;
  const int q = lane >> 4;
  const int n0 = wave * 32;
  const int s0 = blockIdx.x * SPB;

  // A staging map: thread t -> row=t>>4, float4 slots (t&15) + j*16  (j=0..7)
  const int row = tid >> 4;
  const int t15 = tid & 15;
  const float* gbase = enc + ((size_t)s0 * 64 + row) * HID + t15 * 4;
  // dest (shorts): j*4160 + ldbase
  const int ldbase = (t15 >> 3) * 2080 + (((t15 >> 1) & 3) * 65 + row) * 8 + (t15 & 1) * 4;

  const unsigned short* bsrc = wsb + (size_t)(n0 + c) * HID + q * 8;

  float va[2] = { v_a[n0 + c], v_a[n0 + 16 + c] };

  // ---- prologue: stage tile 0 ----
  {
    float4 v[8];
#pragma unroll
    for (int j = 0; j < 8; ++j) v[j] = *(const float4*)(gbase + j * 64);
#pragma unroll
    for (int j = 0; j < 8; ++j) {
      ushort4 o;
      o.x = f2bf(v[j].x); o.y = f2bf(v[j].y); o.z = f2bf(v[j].z); o.w = f2bf(v[j].w);
      *(ushort4*)&Albuf[0][j * 4160 + ldbase] = o;
    }
  }
  __syncthreads();

#pragma unroll 1
  for (int si = 0; si < SPB; ++si) {
    const int cur = si & 1;

    // acc init = dec_att (decT L2-warm): acc[mt][nt][r] = decT[n][mt*16+q*4+r]
    f32x4 acc[4][2];
#pragma unroll
    for (int nt = 0; nt < 2; ++nt)
#pragma unroll
      for (int mt = 0; mt < 4; ++mt)
        acc[mt][nt] = *(const f32x4*)(decT + (size_t)(n0 + nt * 16 + c) * 64 + mt * 16 + q * 4);

    // B prefetch depth 2 (L2) -- issued before the HBM burst is fine: consumed via
    // their own waits; nothing older outstanding except retired prologue.
    short8 bp[2][2];
#pragma unroll
    for (int d = 0; d < 2; ++d)
#pragma unroll
      for (int nt = 0; nt < 2; ++nt)
        bp[d][nt] = *(const short8*)(bsrc + nt * 16 * HID + d * 32);

    // ---- HBM A-burst for tile si+1: all 8 loads issued NOW, consumed after K-loop ----
    const int sil = (si + 1 < SPB) ? si + 1 : si;   // last tile: reload (discarded)
    const float* gnext = gbase + (size_t)sil * (64 * HID);
    float4 stg[8];
#pragma unroll
    for (int j = 0; j < 8; ++j) stg[j] = *(const float4*)(gnext + j * 64);

    // ---- K-loop: 16 steps, only L2 B loads issued inside ----
#pragma unroll
    for (int kk = 0; kk < 16; ++kk) {
      const unsigned short* ab = &Albuf[cur][kk * 2080 + (q * 65 + c) * 8];
      short8 a4[4];
#pragma unroll
      for (int mt = 0; mt < 4; ++mt)
        a4[mt] = *(const short8*)(ab + mt * 128);

#pragma unroll
      for (int mt = 0; mt < 4; ++mt)
#pragma unroll
        for (int nt = 0; nt < 2; ++nt)
          acc[mt][nt] = __builtin_amdgcn_mfma_f32_16x16x32_bf16(a4[mt], bp[kk & 1][nt], acc[mt][nt], 0, 0, 0);

      // reload slot with kk+2 (kk=14,15 overread <200B past wsb into decT: harmless, unused)
#pragma unroll
      for (int nt = 0; nt < 2; ++nt)
        bp[kk & 1][nt] = *(const short8*)(bsrc + nt * 16 * HID + (kk + 2) * 32);
    }

    // ---- consume burst: cvt + write tile si+1 into other LDS buffer ----
#pragma unroll
    for (int j = 0; j < 8; ++j) {
      ushort4 o;
      o.x = f2bf(stg[j].x); o.y = f2bf(stg[j].y);
      o.z = f2bf(stg[j].z); o.w = f2bf(stg[j].w);
      *(ushort4*)&Albuf[cur ^ 1][j * 4160 + ldbase] = o;
    }

    // ---- epilogue: score += v_a * tanh(acc) (dec folded in) ----
    float rowsum[4][4];
#pragma unroll
    for (int mt = 0; mt < 4; ++mt) {
#pragma unroll
      for (int r = 0; r < 4; ++r) {
        float sum = 0.f;
#pragma unroll
        for (int nt = 0; nt < 2; ++nt) {
          float x = acc[mt][nt][r];
          float e = __builtin_amdgcn_exp2f(x * 2.8853900817779268f);
          float t = 1.f - 2.f * __builtin_amdgcn_rcpf(e + 1.f);
          sum = fmaf(va[nt], t, sum);
        }
        rowsum[mt][r] = sum;
      }
    }

    // reduce across the 16 lanes (c) sharing a row
#pragma unroll
    for (int off = 1; off < 16; off <<= 1) {
#pragma unroll
      for (int mt = 0; mt < 4; ++mt)
#pragma unroll
        for (int r = 0; r < 4; ++r)
          rowsum[mt][r] += __shfl_xor(rowsum[mt][r], off, 64);
    }

    if (c == 0) {
#pragma unroll
      for (int mt = 0; mt < 4; ++mt)
#pragma unroll
        for (int r = 0; r < 4; ++r)
          partial[si & 1][wave * 64 + mt * 16 + q * 4 + r] = rowsum[mt][r];
    }

    __syncthreads();   // Albuf[nxt] + partial ready; only L2 B-tails outstanding

    if (tid < 64) {
      float sum = 0.f;
#pragma unroll
      for (int w = 0; w < 16; ++w) sum += partial[si & 1][w * 64 + tid];
      out[(size_t)tid * SEQ + s0 + si] = sum;
    }
  }
}

extern "C" void kernel_launch(void* const* d_in, const int* in_sizes, int n_in,
                              void* d_out, int out_size, void* d_ws, size_t ws_size,
                              hipStream_t stream) {
  const float* dec_out = (const float*)d_in[0];   // (64, 512)
  const float* enc     = (const float*)d_in[1];   // (2048, 64, 512)
  const float* W_s     = (const float*)d_in[2];   // (512, 512)
  const float* W_t     = (const float*)d_in[3];   // (512, 512)
  const float* b_t     = (const float*)d_in[4];   // (512,)
  const float* v_a     = (const float*)d_in[5];   // (512,)
  float* out = (float*)d_out;                     // (64, 2048)

  unsigned short* wsb = (unsigned short*)d_ws;                     // 512 KB: W_s bf16
  float* decT = (float*)((char*)d_ws + (size_t)ATT * HID * 2);     // 128 KB: dec_att^T fp32

  bahdanau_pre<<<128, 256, 0, stream>>>(dec_out, W_t, b_t, W_s, wsb, decT);
  bahdanau_main<<<SEQ / SPB, 1024, 0, stream>>>(enc, wsb, decT, v_a, out);
}

// Round 6
// 491.187 us; speedup vs baseline: 1.1203x; 1.1203x over previous
//
#include <hip/hip_runtime.h>

typedef __attribute__((ext_vector_type(8))) short short8;
typedef __attribute__((ext_vector_type(4))) float f32x4;

#define SEQ 2048
#define BATCH 64
#define HID 512
#define ATT 512

__device__ __forceinline__ unsigned short f2bf(float f) {
  unsigned u = __float_as_uint(f);
  u += 0x7fffu + ((u >> 16) & 1u);   // round-to-nearest-even
  return (unsigned short)(u >> 16);
}

__device__ __forceinline__ void dma16(const void* g, void* l) {
  __builtin_amdgcn_global_load_lds(
      (const __attribute__((address_space(1))) unsigned int*)g,
      (__attribute__((address_space(3))) unsigned int*)l, 16, 0, 0);
}

// Pre-kernel: blocks 0..63 -> decT[a][b] = (W_t@dec_out[b]+b_t)[a] fp32 (transposed);
// blocks 64..127 -> wsb = W_s bf16 in the LDS-image permutation (BIJECTIVE, fixed r5 bug):
//   element (n=a, k=h): chunk c16=h>>5 (16384 shorts each); within chunk the 16B block
//   id is  (n>>4)*64 + ((h>>3)&3)*16 + (n&15)  -> short idx = block*8 + (h&7).
//   b-frag wave reads then hit 64 consecutive blocks (conflict-minimal).
__global__ void bahdanau_pre(const float* __restrict__ dec_out,
                             const float* __restrict__ W_t,
                             const float* __restrict__ b_t,
                             const float* __restrict__ W_s,
                             unsigned short* __restrict__ wsb,
                             float* __restrict__ decT) {
  if (blockIdx.x < 64) {
    const int b = blockIdx.x;
    __shared__ float drow[HID];
    for (int i = threadIdx.x; i < HID; i += 256) drow[i] = dec_out[b * HID + i];
    __syncthreads();
    for (int a = threadIdx.x; a < ATT; a += 256) {
      const float4* wr = (const float4*)(W_t + (size_t)a * HID);
      float s0 = 0.f, s1 = 0.f, s2 = 0.f, s3 = 0.f;
#pragma unroll 4
      for (int j = 0; j < HID / 4; ++j) {
        float4 w = wr[j];
        s0 = fmaf(w.x, drow[4 * j + 0], s0);
        s1 = fmaf(w.y, drow[4 * j + 1], s1);
        s2 = fmaf(w.z, drow[4 * j + 2], s2);
        s3 = fmaf(w.w, drow[4 * j + 3], s3);
      }
      decT[a * BATCH + b] = (s0 + s1) + (s2 + s3) + b_t[a];
    }
  } else {
    const int cb = blockIdx.x - 64;
    const float4* src = (const float4*)W_s;
#pragma unroll
    for (int i = 0; i < 4; ++i) {
      int idx = cb * 1024 + i * 256 + threadIdx.x;   // float4 index over 512x512
      float4 v = src[idx];
      int a = idx >> 7;            // n (row of W_s)
      int h = (idx & 127) * 4;     // first k of the 4
      ushort4 o;
      o.x = f2bf(v.x); o.y = f2bf(v.y); o.z = f2bf(v.z); o.w = f2bf(v.w);
      int blk = (a >> 4) * 64 + ((h >> 3) & 3) * 16 + (a & 15);
      int dst = (h >> 5) * 16384 + blk * 8 + (h & 7);
      *(ushort4*)&wsb[dst] = o;
    }
  }
}

// Main: 2048 blocks x 512 thr (8 waves), one s per block, 2 blocks/CU (80 KB LDS).
// m97 structure: all global->LDS via global_load_lds (A fp32 raw, B bf16 image),
// double-buffered BK=32 K-loop, one barrier per iter, DMA(kb+1) issued post-barrier.
// Zero vmem register loads in the hot loop; A converted fp32->bf16 at frag read.
// A image: DMA (wave w, lane l) fetches A[m=(w&3)*16+(l&15)][4 floats at g=(l>>4)*2+(w>>2)]
//   -> LDS block w*64+l; frag reads (lo: p=0, hi: p=1) are blocks p*256+mt*64+q*16+c
//   (64 consecutive per wave-read). Verified bijective.
__global__ __launch_bounds__(512, 2)
void bahdanau_main(const float* __restrict__ enc,
                   const unsigned short* __restrict__ wsb,
                   const float* __restrict__ decT,
                   const float* __restrict__ v_a,
                   float* __restrict__ out) {
  __shared__ __align__(16) unsigned char smem[81920];     // exactly 80 KB -> 2 blocks/CU
  unsigned short* Bb[2] = { (unsigned short*)smem, (unsigned short*)(smem + 32768) };
  float* Ab[2] = { (float*)(smem + 65536), (float*)(smem + 73728) };
  float* partial = (float*)(smem + 65536);   // aliases Ab[0]; dead by epilogue

  const int tid  = threadIdx.x;
  const int w    = tid >> 6;        // wave 0..7
  const int lane = tid & 63;
  const int c = lane & 15;
  const int q = lane >> 4;
  const int s = blockIdx.x;
  const int n0 = w * 64;

  const char* encB = (const char*)(enc + (size_t)s * 64 * HID);
  const char* wsbB = (const char*)wsb;

  // A DMA per-lane global source for this (w, lane)
  const int am = (w & 3) * 16 + (lane & 15);        // row m
  const int ag = (lane >> 4) * 2 + (w >> 2);        // 4-float group g in the 32-k chunk
  const char* aSrc = encB + am * 2048 + ag * 16;    // + kb*128

  // acc init = dec_att (decT L2-warm): acc[mt][nt][r] = decT[n][mt*16+q*4+r]
  f32x4 acc[4][4];
#pragma unroll
  for (int nt = 0; nt < 4; ++nt)
#pragma unroll
    for (int mt = 0; mt < 4; ++mt)
      acc[mt][nt] = *(const f32x4*)(decT + (size_t)(n0 + nt * 16 + c) * 64 + mt * 16 + q * 4);

  float va[4];
#pragma unroll
  for (int nt = 0; nt < 4; ++nt) va[nt] = v_a[n0 + nt * 16 + c];

  // ---- prologue: DMA tile kb=0 ----
  dma16(aSrc, (char*)Ab[0] + w * 1024);
#pragma unroll
  for (int d = 0; d < 4; ++d)
    dma16(wsbB + w * 4096 + d * 1024 + lane * 16, (char*)Bb[0] + w * 4096 + d * 1024);

#pragma unroll
  for (int kb = 0; kb < 16; ++kb) {
    const int cur = kb & 1;
    __syncthreads();   // drains DMA(kb); covered by the co-resident 2nd block

    if (kb < 15) {
      const int nb = kb + 1;
      const int nxt = nb & 1;
      dma16(aSrc + nb * 128, (char*)Ab[nxt] + w * 1024);
#pragma unroll
      for (int d = 0; d < 4; ++d)
        dma16(wsbB + nb * 32768 + w * 4096 + d * 1024 + lane * 16,
              (char*)Bb[nxt] + w * 4096 + d * 1024);
    }

    // a-frags: A[m=mt*16+c][k=q*8..+7]: lo block mt*64+q*16+c, hi +256 blocks; cvt->bf16
    const float* Ac = Ab[cur];
    const unsigned short* Bc = Bb[cur];
    short8 af[4];
#pragma unroll
    for (int mt = 0; mt < 4; ++mt) {
      float4 lo = *(const float4*)(Ac + (mt * 64 + q * 16 + c) * 4);
      float4 hi = *(const float4*)(Ac + (256 + mt * 64 + q * 16 + c) * 4);
      short8 t;
      t[0] = (short)f2bf(lo.x); t[1] = (short)f2bf(lo.y);
      t[2] = (short)f2bf(lo.z); t[3] = (short)f2bf(lo.w);
      t[4] = (short)f2bf(hi.x); t[5] = (short)f2bf(hi.y);
      t[6] = (short)f2bf(hi.z); t[7] = (short)f2bf(hi.w);
      af[mt] = t;
    }
    // b-frags: block (w*4+nt)*64 + q*16 + c
    short8 bf[4];
#pragma unroll
    for (int nt = 0; nt < 4; ++nt)
      bf[nt] = *(const short8*)(Bc + (((w * 4 + nt) * 64 + q * 16 + c) * 8));

#pragma unroll
    for (int mt = 0; mt < 4; ++mt)
#pragma unroll
      for (int nt = 0; nt < 4; ++nt)
        acc[mt][nt] = __builtin_amdgcn_mfma_f32_16x16x32_bf16(af[mt], bf[nt], acc[mt][nt], 0, 0, 0);
  }

  // ---- epilogue: score += v_a * tanh(acc) (dec folded in) ----
  float rowsum[4][4];
#pragma unroll
  for (int mt = 0; mt < 4; ++mt) {
#pragma unroll
    for (int r = 0; r < 4; ++r) {
      float sum = 0.f;
#pragma unroll
      for (int nt = 0; nt < 4; ++nt) {
        float x = acc[mt][nt][r];
        float e = __builtin_amdgcn_exp2f(x * 2.8853900817779268f);
        float t = 1.f - 2.f * __builtin_amdgcn_rcpf(e + 1.f);
        sum = fmaf(va[nt], t, sum);
      }
      rowsum[mt][r] = sum;
    }
  }

#pragma unroll
  for (int off = 1; off < 16; off <<= 1) {
#pragma unroll
    for (int mt = 0; mt < 4; ++mt)
#pragma unroll
      for (int r = 0; r < 4; ++r)
        rowsum[mt][r] += __shfl_xor(rowsum[mt][r], off, 64);
  }

  // partial aliases Ab[0]: last Ab[0] read (kb=14) is fenced by kb=15's barrier.
  if (c == 0) {
#pragma unroll
    for (int mt = 0; mt < 4; ++mt)
#pragma unroll
      for (int r = 0; r < 4; ++r)
        partial[w * 64 + mt * 16 + q * 4 + r] = rowsum[mt][r];
  }
  __syncthreads();

  if (tid < 64) {
    float sum = 0.f;
#pragma unroll
    for (int ww = 0; ww < 8; ++ww) sum += partial[ww * 64 + tid];
    out[(size_t)tid * SEQ + s] = sum;
  }
}

extern "C" void kernel_launch(void* const* d_in, const int* in_sizes, int n_in,
                              void* d_out, int out_size, void* d_ws, size_t ws_size,
                              hipStream_t stream) {
  const float* dec_out = (const float*)d_in[0];   // (64, 512)
  const float* enc     = (const float*)d_in[1];   // (2048, 64, 512)
  const float* W_s     = (const float*)d_in[2];   // (512, 512)
  const float* W_t     = (const float*)d_in[3];   // (512, 512)
  const float* b_t     = (const float*)d_in[4];   // (512,)
  const float* v_a     = (const float*)d_in[5];   // (512,)
  float* out = (float*)d_out;                     // (64, 2048)

  unsigned short* wsb = (unsigned short*)d_ws;                     // 512 KB: W_s bf16 (LDS image)
  float* decT = (float*)((char*)d_ws + (size_t)ATT * HID * 2);     // 128 KB: dec_att^T fp32

  bahdanau_pre<<<128, 256, 0, stream>>>(dec_out, W_t, b_t, W_s, wsb, decT);
  bahdanau_main<<<SEQ, 512, 0, stream>>>(enc, wsb, decT, v_a, out);
}